// Round 9
// baseline (337.685 us; speedup 1.0000x reference)
//
#include <hip/hip_runtime.h>
#include <hip/hip_bf16.h>

#define B_  2
#define T_  4096
#define C_  768
#define H_  12
#define D_  64
#define MTOT (B_*T_)   // 8192

typedef __bf16 bf16;
typedef __bf16 bf16x8 __attribute__((ext_vector_type(8)));
typedef __bf16 bf16x4 __attribute__((ext_vector_type(4)));
typedef float  f32x4  __attribute__((ext_vector_type(4)));

// async global->LDS, 16B per lane; LDS dest must be wave-uniform base + lane*16
__device__ __forceinline__ void gl_lds16(const bf16* g, bf16* l) {
    __builtin_amdgcn_global_load_lds(
        (const __attribute__((address_space(1))) void*)g,
        (__attribute__((address_space(3))) void*)l, 16, 0, 0);
}

// ---------------- fp32 -> bf16 convert ----------------
__global__ __launch_bounds__(256) void cvt_bf16(const float* __restrict__ src,
                                                bf16* __restrict__ dst, int n8) {
    int i = blockIdx.x * 256 + threadIdx.x;
    if (i >= n8) return;
    const float4* s4 = (const float4*)src;
    float4 a = s4[2*(size_t)i], b = s4[2*(size_t)i+1];
    bf16x8 o;
    o[0]=(bf16)a.x; o[1]=(bf16)a.y; o[2]=(bf16)a.z; o[3]=(bf16)a.w;
    o[4]=(bf16)b.x; o[5]=(bf16)b.y; o[6]=(bf16)b.z; o[7]=(bf16)b.w;
    *(bf16x8*)(dst + 8*(size_t)i) = o;
}

__global__ __launch_bounds__(256) void cvt_bf16_w4(const float* __restrict__ w0,
                                                   const float* __restrict__ w1,
                                                   const float* __restrict__ w2,
                                                   const float* __restrict__ w3,
                                                   bf16* __restrict__ d0,
                                                   bf16* __restrict__ d1,
                                                   bf16* __restrict__ d2,
                                                   bf16* __restrict__ d3) {
    int z = blockIdx.y;
    const float* src = (z==0)?w0:(z==1)?w1:(z==2)?w2:w3;
    bf16* dst = (z==0)?d0:(z==1)?d1:(z==2)?d2:d3;
    int i = blockIdx.x * 256 + threadIdx.x;
    const float4* s4 = (const float4*)src;
    float4 a = s4[2*(size_t)i], b = s4[2*(size_t)i+1];
    bf16x8 o;
    o[0]=(bf16)a.x; o[1]=(bf16)a.y; o[2]=(bf16)a.z; o[3]=(bf16)a.w;
    o[4]=(bf16)b.x; o[5]=(bf16)b.y; o[6]=(bf16)b.z; o[7]=(bf16)b.w;
    *(bf16x8*)(dst + 8*(size_t)i) = o;
}

// ---------------- QKV projection GEMM (BK=64, global_load_lds staging) -------
// z=0 -> Q (pre-scaled by 0.125*log2e) in (B,H,T,D); z=1 -> K; z=2 -> V^T (B,H,D,T)
__global__ __launch_bounds__(256) void gemm_qkv(const bf16* __restrict__ xb,
                                                const bf16* __restrict__ wqb,
                                                const bf16* __restrict__ wkb,
                                                const bf16* __restrict__ wvb,
                                                bf16* __restrict__ qo,
                                                bf16* __restrict__ ko,
                                                bf16* __restrict__ vto) {
    int z = blockIdx.z;
    const bf16* w = (z == 0) ? wqb : (z == 1) ? wkb : wvb;
    bf16* dst = (z == 0) ? qo : (z == 1) ? ko : vto;
    int mbase = blockIdx.x * 128;
    int nbase = blockIdx.y * 128;
    __shared__ bf16 As[128][64];   // UNPADDED: global_load_lds is lane-contiguous
    __shared__ bf16 Bs[128][64];
    int tid  = threadIdx.x;
    int wave = tid >> 6, lane = tid & 63;
    int wm = (wave >> 1) * 64, wn = (wave & 1) * 64;
    int lr = lane & 15, lg = lane >> 4;
    f32x4 acc[4][4] = {};
    for (int kb = 0; kb < C_; kb += 64) {
        #pragma unroll
        for (int it = 0; it < 4; ++it) {
            int ch = tid + it * 256;            // 1024 chunks of 16B per matrix
            int sr = ch >> 3, sc = ch & 7;
            gl_lds16(xb + (size_t)(mbase + sr) * C_ + kb + sc * 8, &As[sr][sc * 8]);
            gl_lds16(w  + (size_t)(nbase + sr) * C_ + kb + sc * 8, &Bs[sr][sc * 8]);
        }
        __syncthreads();           // drains vmcnt(0): DMA complete
        #pragma unroll
        for (int ks = 0; ks < 2; ++ks) {
            bf16x8 af[4], bfr[4];
            #pragma unroll
            for (int mt = 0; mt < 4; ++mt) af[mt]  = *(const bf16x8*)(&As[wm + mt*16 + lr][ks*32 + lg*8]);
            #pragma unroll
            for (int nt = 0; nt < 4; ++nt) bfr[nt] = *(const bf16x8*)(&Bs[wn + nt*16 + lr][ks*32 + lg*8]);
            #pragma unroll
            for (int mt = 0; mt < 4; ++mt)
                #pragma unroll
                for (int nt = 0; nt < 4; ++nt)
                    acc[mt][nt] = __builtin_amdgcn_mfma_f32_16x16x32_bf16(af[mt], bfr[nt], acc[mt][nt], 0, 0, 0);
        }
        __syncthreads();           // reads done before next DMA overwrite
    }
    float sc = (z == 0) ? 0.18033688011112042f : 1.0f;  // 0.125*log2(e) folded into Q
    int m0 = mbase + wm + (lg << 2);
    int n0 = nbase + wn + lr;
    if (z < 2) {
        #pragma unroll
        for (int mt = 0; mt < 4; ++mt) {
            #pragma unroll
            for (int nt = 0; nt < 4; ++nt) {
                int n = n0 + nt * 16;
                int h = n >> 6, d = n & 63;
                #pragma unroll
                for (int r = 0; r < 4; ++r) {
                    int m = m0 + mt * 16 + r;
                    int b = m >> 12, t = m & 4095;
                    dst[(((size_t)b * H_ + h) * T_ + t) * 64 + d] = (bf16)(acc[mt][nt][r] * sc);
                }
            }
        }
    } else {
        #pragma unroll
        for (int mt = 0; mt < 4; ++mt) {
            int m = m0 + mt * 16;
            int b = m >> 12, t = m & 4095;
            #pragma unroll
            for (int nt = 0; nt < 4; ++nt) {
                int n = n0 + nt * 16;
                int h = n >> 6, d = n & 63;
                bf16x4 pk;
                #pragma unroll
                for (int r = 0; r < 4; ++r) pk[r] = (bf16)acc[mt][nt][r];
                *(bf16x4*)(dst + (((size_t)b * H_ + h) * 64 + d) * T_ + t) = pk;
            }
        }
    }
}

// ---------------- output projection GEMM (BK=64 staging) ----------------
__global__ __launch_bounds__(256) void gemm_out(const bf16* __restrict__ ctx,
                                                const bf16* __restrict__ wob,
                                                float* __restrict__ out) {
    int mbase = blockIdx.x * 128;
    int nbase = blockIdx.y * 128;
    __shared__ bf16 As[128][64];
    __shared__ bf16 Bs[128][64];
    int tid  = threadIdx.x;
    int wave = tid >> 6, lane = tid & 63;
    int wm = (wave >> 1) * 64, wn = (wave & 1) * 64;
    int lr = lane & 15, lg = lane >> 4;
    f32x4 acc[4][4] = {};
    for (int kb = 0; kb < C_; kb += 64) {
        #pragma unroll
        for (int it = 0; it < 4; ++it) {
            int ch = tid + it * 256;
            int sr = ch >> 3, sc = ch & 7;
            gl_lds16(ctx + (size_t)(mbase + sr) * C_ + kb + sc * 8, &As[sr][sc * 8]);
            gl_lds16(wob + (size_t)(nbase + sr) * C_ + kb + sc * 8, &Bs[sr][sc * 8]);
        }
        __syncthreads();
        #pragma unroll
        for (int ks = 0; ks < 2; ++ks) {
            bf16x8 af[4], bfr[4];
            #pragma unroll
            for (int mt = 0; mt < 4; ++mt) af[mt]  = *(const bf16x8*)(&As[wm + mt*16 + lr][ks*32 + lg*8]);
            #pragma unroll
            for (int nt = 0; nt < 4; ++nt) bfr[nt] = *(const bf16x8*)(&Bs[wn + nt*16 + lr][ks*32 + lg*8]);
            #pragma unroll
            for (int mt = 0; mt < 4; ++mt)
                #pragma unroll
                for (int nt = 0; nt < 4; ++nt)
                    acc[mt][nt] = __builtin_amdgcn_mfma_f32_16x16x32_bf16(af[mt], bfr[nt], acc[mt][nt], 0, 0, 0);
        }
        __syncthreads();
    }
    int m0 = mbase + wm + (lg << 2);
    int n0 = nbase + wn + lr;
    #pragma unroll
    for (int mt = 0; mt < 4; ++mt)
        #pragma unroll
        for (int nt = 0; nt < 4; ++nt)
            #pragma unroll
            for (int r = 0; r < 4; ++r)
                out[(size_t)(m0 + mt * 16 + r) * C_ + n0 + nt * 16] = acc[mt][nt][r];
}

// ---------------- causal flash attention ----------------
// Round-7 inner loop (K+V in LDS, S^T/O^T, lane-local stats) with
// SORTED-DESCENDING single-tile blocks: grid (64,24), qt = 63 - bx.
// Heaviest blocks dispatch first (LPT): residency rises to ~5 blocks/CU
// (vs pairing's hard 3), tail is the lightest blocks.
__global__ __launch_bounds__(256, 4) void attn(const bf16* __restrict__ q,
                                               const bf16* __restrict__ k,
                                               const bf16* __restrict__ vt,
                                               bf16* __restrict__ ctx) {
    int qt = 63 - blockIdx.x;      // descending work order
    int bh = blockIdx.y;           // 0..23
    int b = bh / H_, h = bh % H_;
    int tid = threadIdx.x;
    int wave = tid >> 6, lane = tid & 63;
    int lr = lane & 15, lg = lane >> 4;

    __shared__ bf16 Ks[64][72];    // K tile (keys x d)
    __shared__ bf16 Vs[64][72];    // V^T tile (d x keys)
    __shared__ bf16 Pb[4][16][72];

    const bf16* qp = q  + (size_t)bh * T_ * 64;
    const bf16* kp = k  + (size_t)bh * T_ * 64;
    const bf16* vp = vt + (size_t)bh * 64 * (size_t)T_;

    int r0 = tid >> 3, c0 = tid & 7;
    const bf16* kstg = kp + (size_t)r0 * 64 + c0 * 8;
    const bf16* vstg = vp + (size_t)r0 * T_ + c0 * 8;

    const float NEGINF = -__builtin_inff();

    int qb = qt * 64 + wave * 16;
    int n  = qt + 1;
    int qrow = qb + lr;

    bf16x8 qf[2];
    #pragma unroll
    for (int c = 0; c < 2; ++c)
        qf[c] = *(const bf16x8*)(qp + (size_t)(qb + lr) * 64 + c * 32 + lg * 8);

    f32x4 o[4] = {};
    float m = NEGINF, l = 0.f;

    uint4 sk0 = *(const uint4*)(kstg);
    uint4 sk1 = *(const uint4*)(kstg + 32 * 64);
    uint4 sv0 = *(const uint4*)(vstg);
    uint4 sv1 = *(const uint4*)(vstg + (size_t)32 * T_);

    for (int kb = 0; kb < n; ++kb) {
        int kv = kb * 64;
        __syncthreads();                       // prev-iter LDS reads complete
        *(uint4*)(&Ks[r0][c0 * 8])      = sk0;
        *(uint4*)(&Ks[32 + r0][c0 * 8]) = sk1;
        *(uint4*)(&Vs[r0][c0 * 8])      = sv0;
        *(uint4*)(&Vs[32 + r0][c0 * 8]) = sv1;
        if (kb + 1 < n) {                      // prefetch next tile
            const bf16* ksrc = kstg + (size_t)(kb + 1) * 64 * 64;
            const bf16* vsrc = vstg + (size_t)(kb + 1) * 64;
            sk0 = *(const uint4*)(ksrc);
            sk1 = *(const uint4*)(ksrc + 32 * 64);
            sv0 = *(const uint4*)(vsrc);
            sv1 = *(const uint4*)(vsrc + (size_t)32 * T_);
        }
        __syncthreads();                       // tile kb visible

        // S^T = K Q^T : rows = keys (A-frag from LDS), cols = q (lane lr)
        f32x4 s[4] = {};
        #pragma unroll
        for (int c2 = 0; c2 < 2; ++c2)
            #pragma unroll
            for (int nt = 0; nt < 4; ++nt) {
                bf16x8 kf = *(const bf16x8*)(&Ks[nt * 16 + lr][c2 * 32 + lg * 8]);
                s[nt] = __builtin_amdgcn_mfma_f32_16x16x32_bf16(kf, qf[c2], s[nt], 0, 0, 0);
            }
        // causal mask (diagonal tile only; Q pre-scaled by 0.125*log2e)
        if (kb == qt) {
            #pragma unroll
            for (int nt = 0; nt < 4; ++nt)
                #pragma unroll
                for (int r = 0; r < 4; ++r) {
                    int key = kv + nt * 16 + lg * 4 + r;
                    s[nt][r] = (key > qrow) ? NEGINF : s[nt][r];
                }
        }
        // online softmax over keys: 16 in-thread + 2-step butterfly
        float mx = s[0][0];
        #pragma unroll
        for (int nt = 0; nt < 4; ++nt) {
            float a = fmaxf(s[nt][0], s[nt][1]);
            float bq = fmaxf(s[nt][2], s[nt][3]);
            mx = fmaxf(mx, fmaxf(a, bq));
        }
        mx = fmaxf(mx, __shfl_xor(mx, 16, 64));
        mx = fmaxf(mx, __shfl_xor(mx, 32, 64));
        float mn = fmaxf(m, mx);
        float al = __builtin_amdgcn_exp2f(m - mn);
        m = mn;
        float sm = 0.f;
        #pragma unroll
        for (int nt = 0; nt < 4; ++nt)
            #pragma unroll
            for (int r = 0; r < 4; ++r) {
                float p = __builtin_amdgcn_exp2f(s[nt][r] - mn);
                s[nt][r] = p;
                sm += p;
            }
        sm += __shfl_xor(sm, 16, 64);
        sm += __shfl_xor(sm, 32, 64);
        l = l * al + sm;
        // O rescale: q-row = lane lr -> alpha is lane-local (no broadcast)
        #pragma unroll
        for (int dt = 0; dt < 4; ++dt)
            #pragma unroll
            for (int r = 0; r < 4; ++r) o[dt][r] *= al;
        // P^T regs -> LDS (per-wave, no barrier) -> B-frags
        #pragma unroll
        for (int nt = 0; nt < 4; ++nt) {
            bf16x4 pk;
            #pragma unroll
            for (int r = 0; r < 4; ++r) pk[r] = (bf16)s[nt][r];
            *(bf16x4*)(&Pb[wave][lr][nt * 16 + lg * 4]) = pk;
        }
        // O^T += V^T P^T : A = V^T frag from LDS, B = P frag
        #pragma unroll
        for (int c2 = 0; c2 < 2; ++c2) {
            bf16x8 pf = *(const bf16x8*)(&Pb[wave][lr][c2 * 32 + lg * 8]);
            #pragma unroll
            for (int dt = 0; dt < 4; ++dt) {
                bf16x8 vfr = *(const bf16x8*)(&Vs[dt * 16 + lr][c2 * 32 + lg * 8]);
                o[dt] = __builtin_amdgcn_mfma_f32_16x16x32_bf16(vfr, pf, o[dt], 0, 0, 0);
            }
        }
    }

    // finalize: q-row = lr (lane-local l); d = dt*16 + lg*4 + r -> 8B stores
    float inv = 1.0f / l;
    #pragma unroll
    for (int dt = 0; dt < 4; ++dt) {
        bf16x4 pk;
        #pragma unroll
        for (int r = 0; r < 4; ++r) pk[r] = (bf16)(o[dt][r] * inv);
        *(bf16x4*)(ctx + ((size_t)b * T_ + qb + lr) * C_ + h * 64 + dt * 16 + lg * 4) = pk;
    }
}

// ---------------- launch ----------------
extern "C" void kernel_launch(void* const* d_in, const int* in_sizes, int n_in,
                              void* d_out, int out_size, void* d_ws, size_t ws_size,
                              hipStream_t stream) {
    const float* x  = (const float*)d_in[0];
    const float* wq = (const float*)d_in[1];
    const float* wk = (const float*)d_in[2];
    const float* wv = (const float*)d_in[3];
    const float* wo = (const float*)d_in[4];
    float* out = (float*)d_out;

    char* ws = (char*)d_ws;
    const size_t SZ_XB = (size_t)MTOT * C_ * sizeof(bf16);
    const size_t SZ_W  = (size_t)C_ * C_ * sizeof(bf16);
    bf16* xb  = (bf16*)(ws);
    bf16* wqb = (bf16*)(ws + SZ_XB);
    bf16* wkb = (bf16*)(ws + SZ_XB + SZ_W);
    bf16* wvb = (bf16*)(ws + SZ_XB + 2 * SZ_W);
    bf16* wob = (bf16*)(ws + SZ_XB + 3 * SZ_W);
    bf16* qb  = (bf16*)(ws + SZ_XB + 4 * SZ_W);
    bf16* kb  = (bf16*)(ws + 2 * SZ_XB + 4 * SZ_W);
    bf16* vtb = (bf16*)(ws + 3 * SZ_XB + 4 * SZ_W);
    bf16* ctb = (bf16*)(ws + 4 * SZ_XB + 4 * SZ_W);

    cvt_bf16<<<3072, 256, 0, stream>>>(x, xb, MTOT * C_ / 8);
    cvt_bf16_w4<<<dim3(288, 4), 256, 0, stream>>>(wq, wk, wv, wo, wqb, wkb, wvb, wob);

    gemm_qkv<<<dim3(MTOT / 128, C_ / 128, 3), 256, 0, stream>>>(xb, wqb, wkb, wvb, qb, kb, vtb);
    attn<<<dim3(64, B_ * H_), 256, 0, stream>>>(qb, kb, vtb, ctb);
    gemm_out<<<dim3(MTOT / 128, C_ / 128), 256, 0, stream>>>(ctb, wob, out);
}

// Round 10
// 250.833 us; speedup vs baseline: 1.3463x; 1.3463x over previous
//
#include <hip/hip_runtime.h>
#include <hip/hip_bf16.h>

#define B_  2
#define T_  4096
#define C_  768
#define H_  12
#define D_  64
#define MTOT (B_*T_)   // 8192

typedef __bf16 bf16;
typedef __bf16 bf16x8 __attribute__((ext_vector_type(8)));
typedef __bf16 bf16x4 __attribute__((ext_vector_type(4)));
typedef float  f32x4  __attribute__((ext_vector_type(4)));

// async global->LDS, 16B per lane; LDS dest must be wave-uniform base + lane*16
__device__ __forceinline__ void gl_lds16(const bf16* g, bf16* l) {
    __builtin_amdgcn_global_load_lds(
        (const __attribute__((address_space(1))) void*)g,
        (__attribute__((address_space(3))) void*)l, 16, 0, 0);
}

// ---------------- fp32 -> bf16 convert ----------------
__global__ __launch_bounds__(256) void cvt_bf16(const float* __restrict__ src,
                                                bf16* __restrict__ dst, int n8) {
    int i = blockIdx.x * 256 + threadIdx.x;
    if (i >= n8) return;
    const float4* s4 = (const float4*)src;
    float4 a = s4[2*(size_t)i], b = s4[2*(size_t)i+1];
    bf16x8 o;
    o[0]=(bf16)a.x; o[1]=(bf16)a.y; o[2]=(bf16)a.z; o[3]=(bf16)a.w;
    o[4]=(bf16)b.x; o[5]=(bf16)b.y; o[6]=(bf16)b.z; o[7]=(bf16)b.w;
    *(bf16x8*)(dst + 8*(size_t)i) = o;
}

__global__ __launch_bounds__(256) void cvt_bf16_w4(const float* __restrict__ w0,
                                                   const float* __restrict__ w1,
                                                   const float* __restrict__ w2,
                                                   const float* __restrict__ w3,
                                                   bf16* __restrict__ d0,
                                                   bf16* __restrict__ d1,
                                                   bf16* __restrict__ d2,
                                                   bf16* __restrict__ d3) {
    int z = blockIdx.y;
    const float* src = (z==0)?w0:(z==1)?w1:(z==2)?w2:w3;
    bf16* dst = (z==0)?d0:(z==1)?d1:(z==2)?d2:d3;
    int i = blockIdx.x * 256 + threadIdx.x;
    const float4* s4 = (const float4*)src;
    float4 a = s4[2*(size_t)i], b = s4[2*(size_t)i+1];
    bf16x8 o;
    o[0]=(bf16)a.x; o[1]=(bf16)a.y; o[2]=(bf16)a.z; o[3]=(bf16)a.w;
    o[4]=(bf16)b.x; o[5]=(bf16)b.y; o[6]=(bf16)b.z; o[7]=(bf16)b.w;
    *(bf16x8*)(dst + 8*(size_t)i) = o;
}

// ---------------- QKV projection GEMM (BK=32 DMA staging — round-8 best) -----
// z=0 -> Q (pre-scaled by 0.125*log2e) in (B,H,T,D); z=1 -> K; z=2 -> V^T (B,H,D,T)
__global__ __launch_bounds__(256) void gemm_qkv(const bf16* __restrict__ xb,
                                                const bf16* __restrict__ wqb,
                                                const bf16* __restrict__ wkb,
                                                const bf16* __restrict__ wvb,
                                                bf16* __restrict__ qo,
                                                bf16* __restrict__ ko,
                                                bf16* __restrict__ vto) {
    int z = blockIdx.z;
    const bf16* w = (z == 0) ? wqb : (z == 1) ? wkb : wvb;
    bf16* dst = (z == 0) ? qo : (z == 1) ? ko : vto;
    int mbase = blockIdx.x * 128;
    int nbase = blockIdx.y * 128;
    __shared__ bf16 As[128][32];   // UNPADDED: global_load_lds is lane-contiguous
    __shared__ bf16 Bs[128][32];
    int tid  = threadIdx.x;
    int wave = tid >> 6, lane = tid & 63;
    int wm = (wave >> 1) * 64, wn = (wave & 1) * 64;
    int lr = lane & 15, lg = lane >> 4;
    int srow0 = tid >> 2, scol0 = tid & 3;
    int srow1 = (tid + 256) >> 2, scol1 = (tid + 256) & 3;
    f32x4 acc[4][4] = {};
    for (int kb = 0; kb < C_; kb += 32) {
        gl_lds16(xb + (size_t)(mbase + srow0) * C_ + kb + scol0 * 8, &As[srow0][scol0 * 8]);
        gl_lds16(xb + (size_t)(mbase + srow1) * C_ + kb + scol1 * 8, &As[srow1][scol1 * 8]);
        gl_lds16(w  + (size_t)(nbase + srow0) * C_ + kb + scol0 * 8, &Bs[srow0][scol0 * 8]);
        gl_lds16(w  + (size_t)(nbase + srow1) * C_ + kb + scol1 * 8, &Bs[srow1][scol1 * 8]);
        __syncthreads();           // drains vmcnt(0): DMA complete
        bf16x8 af[4], bfr[4];
        #pragma unroll
        for (int mt = 0; mt < 4; ++mt) af[mt]  = *(const bf16x8*)(&As[wm + mt*16 + lr][lg*8]);
        #pragma unroll
        for (int nt = 0; nt < 4; ++nt) bfr[nt] = *(const bf16x8*)(&Bs[wn + nt*16 + lr][lg*8]);
        #pragma unroll
        for (int mt = 0; mt < 4; ++mt)
            #pragma unroll
            for (int nt = 0; nt < 4; ++nt)
                acc[mt][nt] = __builtin_amdgcn_mfma_f32_16x16x32_bf16(af[mt], bfr[nt], acc[mt][nt], 0, 0, 0);
        __syncthreads();           // reads done before next DMA overwrite
    }
    float sc = (z == 0) ? 0.18033688011112042f : 1.0f;  // 0.125*log2(e) folded into Q
    int m0 = mbase + wm + (lg << 2);
    int n0 = nbase + wn + lr;
    if (z < 2) {
        #pragma unroll
        for (int mt = 0; mt < 4; ++mt) {
            #pragma unroll
            for (int nt = 0; nt < 4; ++nt) {
                int n = n0 + nt * 16;
                int h = n >> 6, d = n & 63;
                #pragma unroll
                for (int r = 0; r < 4; ++r) {
                    int m = m0 + mt * 16 + r;
                    int b = m >> 12, t = m & 4095;
                    dst[(((size_t)b * H_ + h) * T_ + t) * 64 + d] = (bf16)(acc[mt][nt][r] * sc);
                }
            }
        }
    } else {
        #pragma unroll
        for (int mt = 0; mt < 4; ++mt) {
            int m = m0 + mt * 16;
            int b = m >> 12, t = m & 4095;
            #pragma unroll
            for (int nt = 0; nt < 4; ++nt) {
                int n = n0 + nt * 16;
                int h = n >> 6, d = n & 63;
                bf16x4 pk;
                #pragma unroll
                for (int r = 0; r < 4; ++r) pk[r] = (bf16)acc[mt][nt][r];
                *(bf16x4*)(dst + (((size_t)b * H_ + h) * 64 + d) * T_ + t) = pk;
            }
        }
    }
}

// ---------------- output projection GEMM (BK=32 DMA staging) ----------------
__global__ __launch_bounds__(256) void gemm_out(const bf16* __restrict__ ctx,
                                                const bf16* __restrict__ wob,
                                                float* __restrict__ out) {
    int mbase = blockIdx.x * 128;
    int nbase = blockIdx.y * 128;
    __shared__ bf16 As[128][32];
    __shared__ bf16 Bs[128][32];
    int tid  = threadIdx.x;
    int wave = tid >> 6, lane = tid & 63;
    int wm = (wave >> 1) * 64, wn = (wave & 1) * 64;
    int lr = lane & 15, lg = lane >> 4;
    int srow0 = tid >> 2, scol0 = tid & 3;
    int srow1 = (tid + 256) >> 2, scol1 = (tid + 256) & 3;
    f32x4 acc[4][4] = {};
    for (int kb = 0; kb < C_; kb += 32) {
        gl_lds16(ctx + (size_t)(mbase + srow0) * C_ + kb + scol0 * 8, &As[srow0][scol0 * 8]);
        gl_lds16(ctx + (size_t)(mbase + srow1) * C_ + kb + scol1 * 8, &As[srow1][scol1 * 8]);
        gl_lds16(wob + (size_t)(nbase + srow0) * C_ + kb + scol0 * 8, &Bs[srow0][scol0 * 8]);
        gl_lds16(wob + (size_t)(nbase + srow1) * C_ + kb + scol1 * 8, &Bs[srow1][scol1 * 8]);
        __syncthreads();
        bf16x8 af[4], bfr[4];
        #pragma unroll
        for (int mt = 0; mt < 4; ++mt) af[mt]  = *(const bf16x8*)(&As[wm + mt*16 + lr][lg*8]);
        #pragma unroll
        for (int nt = 0; nt < 4; ++nt) bfr[nt] = *(const bf16x8*)(&Bs[wn + nt*16 + lr][lg*8]);
        #pragma unroll
        for (int mt = 0; mt < 4; ++mt)
            #pragma unroll
            for (int nt = 0; nt < 4; ++nt)
                acc[mt][nt] = __builtin_amdgcn_mfma_f32_16x16x32_bf16(af[mt], bfr[nt], acc[mt][nt], 0, 0, 0);
        __syncthreads();
    }
    int m0 = mbase + wm + (lg << 2);
    int n0 = nbase + wn + lr;
    #pragma unroll
    for (int mt = 0; mt < 4; ++mt)
        #pragma unroll
        for (int nt = 0; nt < 4; ++nt)
            #pragma unroll
            for (int r = 0; r < 4; ++r)
                out[(size_t)(m0 + mt * 16 + r) * C_ + n0 + nt * 16] = acc[mt][nt][r];
}

// ---------------- causal flash attention ----------------
// Round-7 inner loop (K+V in LDS, S^T/O^T, lane-local stats) with GLOBAL LPT
// dispatch: 1-D grid of 1536, qt = 63 - idx/24 (monotone descending across
// the WHOLE dispatch), bh = idx%24. Heaviest 1280 jobs (5 blocks/CU by LDS)
// start at t=0; queued 256 are the lightest (avg ~5 iters) -> tiny tail.
// Round-9 lesson: per-row descending (24 runs) put heavy jobs at the END.
__global__ __launch_bounds__(256, 4) void attn(const bf16* __restrict__ q,
                                               const bf16* __restrict__ k,
                                               const bf16* __restrict__ vt,
                                               bf16* __restrict__ ctx) {
    int idx = blockIdx.x;          // 0..1535
    int qt = 63 - idx / 24;        // globally sorted descending work
    int bh = idx % 24;
    int b = bh / H_, h = bh % H_;
    int tid = threadIdx.x;
    int wave = tid >> 6, lane = tid & 63;
    int lr = lane & 15, lg = lane >> 4;

    __shared__ bf16 Ks[64][72];    // K tile (keys x d)
    __shared__ bf16 Vs[64][72];    // V^T tile (d x keys)
    __shared__ bf16 Pb[4][16][72];

    const bf16* qp = q  + (size_t)bh * T_ * 64;
    const bf16* kp = k  + (size_t)bh * T_ * 64;
    const bf16* vp = vt + (size_t)bh * 64 * (size_t)T_;

    int r0 = tid >> 3, c0 = tid & 7;
    const bf16* kstg = kp + (size_t)r0 * 64 + c0 * 8;
    const bf16* vstg = vp + (size_t)r0 * T_ + c0 * 8;

    const float NEGINF = -__builtin_inff();

    int qb = qt * 64 + wave * 16;
    int n  = qt + 1;
    int qrow = qb + lr;

    bf16x8 qf[2];
    #pragma unroll
    for (int c = 0; c < 2; ++c)
        qf[c] = *(const bf16x8*)(qp + (size_t)(qb + lr) * 64 + c * 32 + lg * 8);

    f32x4 o[4] = {};
    float m = NEGINF, l = 0.f;

    uint4 sk0 = *(const uint4*)(kstg);
    uint4 sk1 = *(const uint4*)(kstg + 32 * 64);
    uint4 sv0 = *(const uint4*)(vstg);
    uint4 sv1 = *(const uint4*)(vstg + (size_t)32 * T_);

    for (int kb = 0; kb < n; ++kb) {
        int kv = kb * 64;
        __syncthreads();                       // prev-iter LDS reads complete
        *(uint4*)(&Ks[r0][c0 * 8])      = sk0;
        *(uint4*)(&Ks[32 + r0][c0 * 8]) = sk1;
        *(uint4*)(&Vs[r0][c0 * 8])      = sv0;
        *(uint4*)(&Vs[32 + r0][c0 * 8]) = sv1;
        if (kb + 1 < n) {                      // prefetch next tile
            const bf16* ksrc = kstg + (size_t)(kb + 1) * 64 * 64;
            const bf16* vsrc = vstg + (size_t)(kb + 1) * 64;
            sk0 = *(const uint4*)(ksrc);
            sk1 = *(const uint4*)(ksrc + 32 * 64);
            sv0 = *(const uint4*)(vsrc);
            sv1 = *(const uint4*)(vsrc + (size_t)32 * T_);
        }
        __syncthreads();                       // tile kb visible

        // S^T = K Q^T : rows = keys (A-frag from LDS), cols = q (lane lr)
        f32x4 s[4] = {};
        #pragma unroll
        for (int c2 = 0; c2 < 2; ++c2)
            #pragma unroll
            for (int nt = 0; nt < 4; ++nt) {
                bf16x8 kf = *(const bf16x8*)(&Ks[nt * 16 + lr][c2 * 32 + lg * 8]);
                s[nt] = __builtin_amdgcn_mfma_f32_16x16x32_bf16(kf, qf[c2], s[nt], 0, 0, 0);
            }
        // causal mask (diagonal tile only; Q pre-scaled by 0.125*log2e)
        if (kb == qt) {
            #pragma unroll
            for (int nt = 0; nt < 4; ++nt)
                #pragma unroll
                for (int r = 0; r < 4; ++r) {
                    int key = kv + nt * 16 + lg * 4 + r;
                    s[nt][r] = (key > qrow) ? NEGINF : s[nt][r];
                }
        }
        // online softmax over keys: 16 in-thread + 2-step butterfly
        float mx = s[0][0];
        #pragma unroll
        for (int nt = 0; nt < 4; ++nt) {
            float a = fmaxf(s[nt][0], s[nt][1]);
            float bq = fmaxf(s[nt][2], s[nt][3]);
            mx = fmaxf(mx, fmaxf(a, bq));
        }
        mx = fmaxf(mx, __shfl_xor(mx, 16, 64));
        mx = fmaxf(mx, __shfl_xor(mx, 32, 64));
        float mn = fmaxf(m, mx);
        float al = __builtin_amdgcn_exp2f(m - mn);
        m = mn;
        float sm = 0.f;
        #pragma unroll
        for (int nt = 0; nt < 4; ++nt)
            #pragma unroll
            for (int r = 0; r < 4; ++r) {
                float p = __builtin_amdgcn_exp2f(s[nt][r] - mn);
                s[nt][r] = p;
                sm += p;
            }
        sm += __shfl_xor(sm, 16, 64);
        sm += __shfl_xor(sm, 32, 64);
        l = l * al + sm;
        // O rescale: q-row = lane lr -> alpha is lane-local (no broadcast)
        #pragma unroll
        for (int dt = 0; dt < 4; ++dt)
            #pragma unroll
            for (int r = 0; r < 4; ++r) o[dt][r] *= al;
        // P^T regs -> LDS (per-wave, no barrier) -> B-frags
        #pragma unroll
        for (int nt = 0; nt < 4; ++nt) {
            bf16x4 pk;
            #pragma unroll
            for (int r = 0; r < 4; ++r) pk[r] = (bf16)s[nt][r];
            *(bf16x4*)(&Pb[wave][lr][nt * 16 + lg * 4]) = pk;
        }
        // O^T += V^T P^T : A = V^T frag from LDS, B = P frag
        #pragma unroll
        for (int c2 = 0; c2 < 2; ++c2) {
            bf16x8 pf = *(const bf16x8*)(&Pb[wave][lr][c2 * 32 + lg * 8]);
            #pragma unroll
            for (int dt = 0; dt < 4; ++dt) {
                bf16x8 vfr = *(const bf16x8*)(&Vs[dt * 16 + lr][c2 * 32 + lg * 8]);
                o[dt] = __builtin_amdgcn_mfma_f32_16x16x32_bf16(vfr, pf, o[dt], 0, 0, 0);
            }
        }
    }

    // finalize: q-row = lr (lane-local l); d = dt*16 + lg*4 + r -> 8B stores
    float inv = 1.0f / l;
    #pragma unroll
    for (int dt = 0; dt < 4; ++dt) {
        bf16x4 pk;
        #pragma unroll
        for (int r = 0; r < 4; ++r) pk[r] = (bf16)(o[dt][r] * inv);
        *(bf16x4*)(ctx + ((size_t)b * T_ + qb + lr) * C_ + h * 64 + dt * 16 + lg * 4) = pk;
    }
}

// ---------------- launch ----------------
extern "C" void kernel_launch(void* const* d_in, const int* in_sizes, int n_in,
                              void* d_out, int out_size, void* d_ws, size_t ws_size,
                              hipStream_t stream) {
    const float* x  = (const float*)d_in[0];
    const float* wq = (const float*)d_in[1];
    const float* wk = (const float*)d_in[2];
    const float* wv = (const float*)d_in[3];
    const float* wo = (const float*)d_in[4];
    float* out = (float*)d_out;

    char* ws = (char*)d_ws;
    const size_t SZ_XB = (size_t)MTOT * C_ * sizeof(bf16);
    const size_t SZ_W  = (size_t)C_ * C_ * sizeof(bf16);
    bf16* xb  = (bf16*)(ws);
    bf16* wqb = (bf16*)(ws + SZ_XB);
    bf16* wkb = (bf16*)(ws + SZ_XB + SZ_W);
    bf16* wvb = (bf16*)(ws + SZ_XB + 2 * SZ_W);
    bf16* wob = (bf16*)(ws + SZ_XB + 3 * SZ_W);
    bf16* qb  = (bf16*)(ws + SZ_XB + 4 * SZ_W);
    bf16* kb  = (bf16*)(ws + 2 * SZ_XB + 4 * SZ_W);
    bf16* vtb = (bf16*)(ws + 3 * SZ_XB + 4 * SZ_W);
    bf16* ctb = (bf16*)(ws + 4 * SZ_XB + 4 * SZ_W);

    cvt_bf16<<<3072, 256, 0, stream>>>(x, xb, MTOT * C_ / 8);
    cvt_bf16_w4<<<dim3(288, 4), 256, 0, stream>>>(wq, wk, wv, wo, wqb, wkb, wvb, wob);

    gemm_qkv<<<dim3(MTOT / 128, C_ / 128, 3), 256, 0, stream>>>(xb, wqb, wkb, wvb, qb, kb, vtb);
    attn<<<1536, 256, 0, stream>>>(qb, kb, vtb, ctb);
    gemm_out<<<dim3(MTOT / 128, C_ / 128), 256, 0, stream>>>(ctb, wob, out);
}